// Round 1
// baseline (388.030 us; speedup 1.0000x reference)
//
#include <hip/hip_runtime.h>

#define N_NEURONS 100000
#define MAX_DELAY 5
#define NSYN 5
#define T_STEPS 20
#define N_LGN 17400
#define N_BKG 100
#define E_REC 2000000
#define E_LGN 600000
#define E_BKG 200000
#define DT 1.0f

// ---------------- ws layout (floats) ----------------
// inp_buf   : [T][NSYN][N]      10,000,000
// zbuf      : [MAX_DELAY][N]       500,000   (circular: z(t) at slot t%5)
// psc_rise  : [NSYN][N]            500,000
// psc       : [NSYN][N]            500,000
// v         : [N]                  100,000
// r         : [N]                  100,000
// asc       : [N][2]               200,000
// counts    : int[32]                   32
// total floats = 11,900,032  (~45.4 MB)

__global__ void zero_ws(float* __restrict__ ws, long n4) {
    long i = (long)blockIdx.x * blockDim.x + threadIdx.x;
    long stride = (long)gridDim.x * blockDim.x;
    float4* p = (float4*)ws;
    float4 z = make_float4(0.f, 0.f, 0.f, 0.f);
    for (long j = i; j < n4; j += stride) p[j] = z;
}

// Precompute external (LGN + BKG) synaptic input for all timesteps.
__global__ void ext_scatter(const float* __restrict__ lgn_spk, const float* __restrict__ bkg_spk,
                            const int* __restrict__ lgn_idx, const float* __restrict__ lgn_w,
                            const float* __restrict__ lgn_fac,
                            const int* __restrict__ bkg_idx, const float* __restrict__ bkg_w,
                            const float* __restrict__ bkg_fac,
                            float* __restrict__ inp_buf) {
    int e = blockIdx.x * blockDim.x + threadIdx.x;
    const int* idx; const float* wp; const float* fp; const float* spk; int ncols;
    if (e < E_LGN) {
        idx = lgn_idx; wp = lgn_w; fp = lgn_fac; spk = lgn_spk; ncols = N_LGN;
    } else {
        e -= E_LGN;
        if (e >= E_BKG) return;
        idx = bkg_idx; wp = bkg_w; fp = bkg_fac; spk = bkg_spk; ncols = N_BKG;
    }
    int post = idx[2 * e];
    int src  = idx[2 * e + 1];
    float w  = wp[e];
    float f0 = fp[5*e], f1 = fp[5*e+1], f2 = fp[5*e+2], f3 = fp[5*e+3], f4 = fp[5*e+4];
    for (int t = 0; t < T_STEPS; ++t) {
        float s = spk[t * ncols + src];
        if (s != 0.0f) {
            float sw = s * w;
            float* base = inp_buf + (size_t)t * NSYN * N_NEURONS + post;
            atomicAdd(base,                  sw * f0);
            atomicAdd(base + N_NEURONS,      sw * f1);
            atomicAdd(base + 2 * N_NEURONS,  sw * f2);
            atomicAdd(base + 3 * N_NEURONS,  sw * f3);
            atomicAdd(base + 4 * N_NEURONS,  sw * f4);
        }
    }
}

// Recurrent scatter for step t; gated on spike counts of the last MAX_DELAY steps.
__global__ void rec_scatter(const int* __restrict__ rec_idx, const float* __restrict__ rec_w,
                            const float* __restrict__ rec_fac,
                            const float* __restrict__ zbuf, const int* __restrict__ counts,
                            float* __restrict__ inp_t, int t) {
    int any = 0;
#pragma unroll
    for (int d = 1; d <= MAX_DELAY; ++d) {
        int j = t - d;
        if (j >= 0) any += counts[j];
    }
    if (any == 0) return;   // no spikes in the visible window -> nothing to do

    int tid = blockIdx.x * blockDim.x + threadIdx.x;
    int stride = gridDim.x * blockDim.x;
    for (int e = tid; e < E_REC; e += stride) {
        int post = rec_idx[2 * e];
        int col  = rec_idx[2 * e + 1];
        int d1   = col / N_NEURONS;          // delay - 1
        int pre  = col - d1 * N_NEURONS;
        int srcstep = t - 1 - d1;            // = t - delay
        if (srcstep < 0) continue;
        float s = zbuf[(srcstep % MAX_DELAY) * N_NEURONS + pre];
        if (s == 0.0f) continue;
        float sw = s * rec_w[e];
        float* base = inp_t + post;
        atomicAdd(base,                  sw * rec_fac[5*e]);
        atomicAdd(base + N_NEURONS,      sw * rec_fac[5*e+1]);
        atomicAdd(base + 2 * N_NEURONS,  sw * rec_fac[5*e+2]);
        atomicAdd(base + 3 * N_NEURONS,  sw * rec_fac[5*e+3]);
        atomicAdd(base + 4 * N_NEURONS,  sw * rec_fac[5*e+4]);
    }
}

__global__ void neuron_update(float* __restrict__ zbuf,
                              float* __restrict__ psc_rise, float* __restrict__ psc,
                              float* __restrict__ v, float* __restrict__ r,
                              float* __restrict__ asc,
                              const float* __restrict__ inp_t,
                              const float* __restrict__ decay,
                              const float* __restrict__ current_factor,
                              const float* __restrict__ v_reset,
                              const float* __restrict__ t_ref,
                              const float* __restrict__ k,
                              const float* __restrict__ asc_amps,
                              const float* __restrict__ v_th,
                              const float* __restrict__ normalizer,
                              const float* __restrict__ g,
                              const float* __restrict__ syn_decay,
                              const float* __restrict__ psc_initial,
                              float* __restrict__ out, int* __restrict__ counts, int t) {
    int n = blockIdx.x * blockDim.x + threadIdx.x;
    bool fired = false;
    if (n < N_NEURONS) {
        float prev_z = (t == 0) ? 0.0f : zbuf[((t - 1) % MAX_DELAY) * N_NEURONS + n];

        float pr[NSYN], pc[NSYN];
        float ic = 0.0f;
#pragma unroll
        for (int s = 0; s < NSYN; ++s) {
            pr[s] = psc_rise[(size_t)s * N_NEURONS + n];
            pc[s] = psc[(size_t)s * N_NEURONS + n];
            ic += pc[s];            // input_current uses OLD psc
        }
        float a0 = asc[2 * n], a1 = asc[2 * n + 1];
        float c1 = ic + a0 + a1 + g[n];
        float dv = decay[n] * v[n] + current_factor[n] * c1;
        float nv = (prev_z > 0.5f) ? v_reset[n] : dv;
        float tr = t_ref[n];
        float nr = r[n] + prev_z * tr - DT;
        nr = fminf(fmaxf(nr, 0.0f), tr);
        float na0 = expf(-DT * k[2 * n])     * a0 + prev_z * asc_amps[2 * n];
        float na1 = expf(-DT * k[2 * n + 1]) * a1 + prev_z * asc_amps[2 * n + 1];

#pragma unroll
        for (int s = 0; s < NSYN; ++s) {
            float sd  = syn_decay[s];
            float npc = pc[s] * sd + DT * sd * pr[s];                 // uses OLD psc_rise
            float npr = pr[s] * sd + inp_t[(size_t)s * N_NEURONS + n] * psc_initial[s];
            psc[(size_t)s * N_NEURONS + n]      = npc;
            psc_rise[(size_t)s * N_NEURONS + n] = npr;
        }
        v[n] = nv; r[n] = nr; asc[2 * n] = na0; asc[2 * n + 1] = na1;

        float vsc = (nv - v_th[n]) / normalizer[n];
        float z   = (vsc > 0.0f) ? 1.0f : 0.0f;
        float nz  = (nr > 0.0f) ? 0.0f : z;
        zbuf[(t % MAX_DELAY) * N_NEURONS + n] = nz;
        out[(size_t)t * N_NEURONS + n] = nz;
        fired = (nz != 0.0f);
    }
    unsigned long long m = __ballot(fired);
    if (m && (threadIdx.x & 63) == 0) atomicAdd(&counts[t], (int)__popcll(m));
}

extern "C" void kernel_launch(void* const* d_in, const int* in_sizes, int n_in,
                              void* d_out, int out_size, void* d_ws, size_t ws_size,
                              hipStream_t stream) {
    const float* lgn_spikes  = (const float*)d_in[0];
    const float* bkg_spikes  = (const float*)d_in[1];
    const int*   rec_indices = (const int*)  d_in[2];
    const float* rec_w       = (const float*)d_in[3];
    const float* rec_factors = (const float*)d_in[4];
    const int*   lgn_indices = (const int*)  d_in[5];
    const float* lgn_w       = (const float*)d_in[6];
    const float* lgn_factors = (const float*)d_in[7];
    const int*   bkg_indices = (const int*)  d_in[8];
    const float* bkg_w       = (const float*)d_in[9];
    const float* bkg_factors = (const float*)d_in[10];
    const float* decay       = (const float*)d_in[11];
    const float* current_factor = (const float*)d_in[12];
    const float* v_reset     = (const float*)d_in[13];
    const float* t_ref       = (const float*)d_in[14];
    const float* k           = (const float*)d_in[15];
    const float* asc_amps    = (const float*)d_in[16];
    const float* v_th        = (const float*)d_in[17];
    const float* normalizer  = (const float*)d_in[18];
    const float* gathered_g  = (const float*)d_in[19];
    const float* syn_decay   = (const float*)d_in[20];
    const float* psc_initial = (const float*)d_in[21];

    float* ws       = (float*)d_ws;
    float* inp_buf  = ws;
    float* zbuf     = inp_buf + (size_t)T_STEPS * NSYN * N_NEURONS;  // +10,000,000
    float* psc_rise = zbuf + (size_t)MAX_DELAY * N_NEURONS;          // +500,000
    float* psc      = psc_rise + (size_t)NSYN * N_NEURONS;           // +500,000
    float* vv       = psc + (size_t)NSYN * N_NEURONS;                // +500,000
    float* rr       = vv + N_NEURONS;
    float* asc      = rr + N_NEURONS;
    int*   counts   = (int*)(asc + 2 * (size_t)N_NEURONS);

    long total_floats = 11900032;  // includes counts (32 ints)
    zero_ws<<<2048, 256, 0, stream>>>(ws, total_floats / 4);

    ext_scatter<<<(E_LGN + E_BKG + 255) / 256, 256, 0, stream>>>(
        lgn_spikes, bkg_spikes,
        lgn_indices, lgn_w, lgn_factors,
        bkg_indices, bkg_w, bkg_factors,
        inp_buf);

    float* out = (float*)d_out;
    for (int t = 0; t < T_STEPS; ++t) {
        if (t > 0) {
            rec_scatter<<<2048, 256, 0, stream>>>(
                rec_indices, rec_w, rec_factors, zbuf, counts,
                inp_buf + (size_t)t * NSYN * N_NEURONS, t);
        }
        neuron_update<<<(N_NEURONS + 255) / 256, 256, 0, stream>>>(
            zbuf, psc_rise, psc, vv, rr, asc,
            inp_buf + (size_t)t * NSYN * N_NEURONS,
            decay, current_factor, v_reset, t_ref, k, asc_amps,
            v_th, normalizer, gathered_g, syn_decay, psc_initial,
            out, counts, t);
    }
}